// Round 16
// baseline (110.964 us; speedup 1.0000x reference)
//
#include <hip/hip_runtime.h>
#include <hip/hip_fp16.h>

// Problem constants
#define BATCH   4
#define SEQ     4096
#define DMODEL  1024
#define HDIM    120
#define ROWS_TOTAL (BATCH * SEQ)       // 16384
#define TPB     256                    // 16-row tiles per batch (SEQ/16)

typedef float f32x4 __attribute__((ext_vector_type(4)));
typedef short s16x8 __attribute__((ext_vector_type(8)));

// F layout (fragment-ordered ctx): s16x8 F[global_tile][ks][lane]
//   = ctx_n[tile*16 + (lane&15)][ks*32 + (lane>>4)*8 .. +8]  (bf16)
#define FRAG_PER_B ((size_t)TPB * 4 * 64)
// WF layout (fragment-ordered Wq*wt, bf16): s16x8 WF[(ct*32+ks)*64 + lane]

static __device__ __forceinline__ unsigned short f2bf(float f) {
    unsigned u = __float_as_uint(f);
    u += 0x7FFFu + ((u >> 16) & 1u);   // RNE
    return (unsigned short)(u >> 16);
}
static __device__ __forceinline__ s16x8 pack2x4(f32x4 lo, f32x4 hi) {
    s16x8 r;
#pragma unroll
    for (int i = 0; i < 4; ++i) r[i] = (short)f2bf(lo[i]);
#pragma unroll
    for (int i = 0; i < 4; ++i) r[4 + i] = (short)f2bf(hi[i]);
    return r;
}

// ---------------------------------------------------------------------------
// Kernel W (unchanged): Wq -> WF fragment-ordered bf16, wt folded in.
// ---------------------------------------------------------------------------
__global__ __launch_bounds__(64)
void wq_frag_kernel(const float* __restrict__ Wq, const float* __restrict__ wt,
                    s16x8* __restrict__ WF)
{
    const int lane = threadIdx.x;
    const int l15  = lane & 15;
    const int l4   = lane >> 4;
    const int ct   = blockIdx.x >> 5;
    const int ks   = blockIdx.x & 31;
    const int col  = ct * 16 + l15;

    f32x4 lo = (f32x4){0.f,0.f,0.f,0.f}, hi = lo;
    if (col < HDIM) {
        const float w = wt[col];
        const float* src = Wq + (size_t)col * DMODEL + ks * 32 + l4 * 8;
        lo = *(const f32x4*)(src);
        hi = *(const f32x4*)(src + 4);
#pragma unroll
        for (int i = 0; i < 4; ++i) { lo[i] *= w; hi[i] *= w; }
    }
    WF[((size_t)(ct * 32 + ks)) * 64 + lane] = pack2x4(lo, hi);
}

// ---------------------------------------------------------------------------
// Kernel A v3 (unchanged from R15): context GEMM + bias + L2-norm -> F.
// ---------------------------------------------------------------------------
__global__ __launch_bounds__(512)
void ctx_norm_kernel(const float* __restrict__ query,
                     const s16x8* __restrict__ WF,
                     const float* __restrict__ bq,
                     const float* __restrict__ wt,
                     s16x8* __restrict__ F)
{
    __shared__ unsigned short lA[2][32 * 72];
    __shared__ float lsq[32][4];
    __shared__ unsigned short lt[32][136];

    const int tid  = threadIdx.x;
    const int lane = tid & 63;
    const int wv   = tid >> 6;
    const int wr   = wv & 1;
    const int wc   = wv >> 1;
    const int l15  = lane & 15;
    const int l4   = lane >> 4;
    const int row0 = blockIdx.x * 32;

    const int arow = tid >> 4;
    const int achk = tid & 15;
    const float* aload = query + (size_t)(row0 + arow) * DMODEL + achk * 4;

    f32x4 acc[2];
#pragma unroll
    for (int n = 0; n < 2; ++n) acc[n] = (f32x4){0.f,0.f,0.f,0.f};

    auto stage = [&](int buf, const f32x4& v) {
        const unsigned u0 = (unsigned)f2bf(v[0]) | ((unsigned)f2bf(v[1]) << 16);
        const unsigned u1 = (unsigned)f2bf(v[2]) | ((unsigned)f2bf(v[3]) << 16);
        *(uint2*)&lA[buf][arow * 72 + achk * 4] = make_uint2(u0, u1);
    };

    f32x4 pr = *(const f32x4*)(aload);
    stage(0, pr);

    for (int slab = 0; slab < 16; ++slab) {
        __syncthreads();
        if (slab + 1 < 16) pr = *(const f32x4*)(aload + (slab + 1) * 64);
        const int buf = slab & 1;
#pragma unroll
        for (int ks2 = 0; ks2 < 2; ++ks2) {
            const int ks = slab * 2 + ks2;
            const s16x8 a = *(const s16x8*)&lA[buf][(wr * 16 + l15) * 72 + ks2 * 32 + l4 * 8];
#pragma unroll
            for (int n = 0; n < 2; ++n) {
                const s16x8 bfr = WF[((size_t)((wc * 2 + n) * 32 + ks)) * 64 + lane];
                acc[n] = __builtin_amdgcn_mfma_f32_16x16x32_bf16(a, bfr, acc[n], 0, 0, 0);
            }
        }
        if (slab + 1 < 16) stage(buf ^ 1, pr);
    }

    float sumsq[4] = {0.f,0.f,0.f,0.f};
#pragma unroll
    for (int n = 0; n < 2; ++n) {
        const int col = wc * 32 + n * 16 + l15;
        const float bqv = (col < HDIM) ? bq[col] * wt[col] : 0.f;
#pragma unroll
        for (int r = 0; r < 4; ++r) {
            const float v = acc[n][r] + bqv;
            acc[n][r] = v;
            sumsq[r] += v * v;
        }
    }
#pragma unroll
    for (int r = 0; r < 4; ++r) {
        float s = sumsq[r];
        s += __shfl_xor(s, 1);
        s += __shfl_xor(s, 2);
        s += __shfl_xor(s, 4);
        s += __shfl_xor(s, 8);
        sumsq[r] = s;
    }
    if (l15 == 0) {
#pragma unroll
        for (int r = 0; r < 4; ++r)
            lsq[wr * 16 + l4 * 4 + r][wc] = sumsq[r];
    }
    __syncthreads();
#pragma unroll
    for (int r = 0; r < 4; ++r) {
        const int lr = wr * 16 + l4 * 4 + r;
        const float s = lsq[lr][0] + lsq[lr][1] + lsq[lr][2] + lsq[lr][3];
        const float rinv = 1.f / fmaxf(sqrtf(s), 1e-12f);
#pragma unroll
        for (int n = 0; n < 2; ++n)
            lt[lr][wc * 32 + n * 16 + l15] = f2bf(acc[n][r] * rinv);
    }
    __syncthreads();
    {
        const int tl = wv >> 2;
        const int k4 = wv & 3;
        const s16x8 fr = *(const s16x8*)&lt[tl * 16 + l15][k4 * 32 + l4 * 8];
        F[((size_t)(blockIdx.x * 2 + tl) * 4 + k4) * 64 + lane] = fr;
    }
}

// ---------------------------------------------------------------------------
// Kernel B1 (== R14, proven): rowsum -> rinv[global_row] = 1/sum(exp), f32.
// 512 blocks x 512 thr; block = 32 rows x 4096 cols; zero stores in hot loop.
// ---------------------------------------------------------------------------
__global__ __launch_bounds__(512, 4)
void rowsum_kernel(const s16x8* __restrict__ F, float* __restrict__ rinv)
{
    __shared__ float lsum[32][8];

    const int tid  = threadIdx.x;
    const int lane = tid & 63;
    const int cg   = tid >> 6;
    const int l15  = lane & 15;

    const int u    = ((blockIdx.x & 7) << 6) | (blockIdx.x >> 3);  // bijective on 512
    const int b    = u >> 7;
    const int rg   = u & 127;
    const s16x8* Fb = F + (size_t)b * FRAG_PER_B;

    s16x8 rfA[4], rfB[4];
#pragma unroll
    for (int ks = 0; ks < 4; ++ks) {
        rfA[ks] = Fb[((size_t)(rg * 2) * 4 + ks) * 64 + lane];
        rfB[ks] = Fb[((size_t)(rg * 2 + 1) * 4 + ks) * 64 + lane];
    }

    const s16x8* base = Fb + (size_t)(cg * 32) * 256 + lane;
    float rsA = 0.f, rsB = 0.f;

    s16x8 cf0[4], cf1[4];
    auto loadC = [&](s16x8* cf, int t) {
        const s16x8* p = base + (size_t)t * 256;
#pragma unroll
        for (int ks = 0; ks < 4; ++ks) cf[ks] = p[ks * 64];
    };
    auto accum = [&](const s16x8* cf) {
        f32x4 aA = (f32x4){0.f,0.f,0.f,0.f};
        f32x4 aB = (f32x4){0.f,0.f,0.f,0.f};
#pragma unroll
        for (int ks = 0; ks < 4; ++ks) {
            aA = __builtin_amdgcn_mfma_f32_16x16x32_bf16(cf[ks], rfA[ks], aA, 0, 0, 0);
            aB = __builtin_amdgcn_mfma_f32_16x16x32_bf16(cf[ks], rfB[ks], aB, 0, 0, 0);
        }
#pragma unroll
        for (int j = 0; j < 4; ++j) {
            rsA += __expf(aA[j]);
            rsB += __expf(aB[j]);
        }
    };

    loadC(cf0, 0);
    loadC(cf1, 1);
    for (int t = 0; t < 32; t += 2) {
        accum(cf0);
        if (t + 2 < 32) loadC(cf0, t + 2);
        accum(cf1);
        if (t + 3 < 32) loadC(cf1, t + 3);
    }

    rsA += __shfl_xor(rsA, 16);
    rsA += __shfl_xor(rsA, 32);
    rsB += __shfl_xor(rsB, 16);
    rsB += __shfl_xor(rsB, 32);
    if (lane < 16) {
        lsum[l15][cg]      = rsA;
        lsum[16 + l15][cg] = rsB;
    }
    __syncthreads();
    if (tid < 32) {
        float s = 0.f;
#pragma unroll
        for (int w = 0; w < 8; ++w) s += lsum[tid][w];
        rinv[(b * 128 + rg) * 32 + tid] = 1.f / s;   // == rinv[global_row]
    }
}

// ---------------------------------------------------------------------------
// Kernel B2: wave-private writer — ZERO barriers, no phase lock.
// 1024 blocks x 512 thr (8 waves); block = one 16-row tile x 4096 cols.
// Each wave independently: for 2 strips of 256 cols: {compute 16 col-tiles
// (depth-3 prefetch) -> exp -> f16 into PRIVATE 8KB LDS} then {16 rows x
// 1KB full-line NT stores}. Waves drift out of phase -> every CU always has
// both MFMA work and store drain in flight. LDS 64KB, VGPR<=128 -> 2 blk/CU.
// ---------------------------------------------------------------------------
#define LOADW(dst, t) { const s16x8* _p = base + (size_t)(t) * 256;            \
    dst[0] = _p[0]; dst[1] = _p[64]; dst[2] = _p[128]; dst[3] = _p[192]; }

#define COMPW(src, t) { f32x4 _a = (f32x4){0.f, 0.f, 0.f, 0.f};                \
    _a = __builtin_amdgcn_mfma_f32_16x16x32_bf16(src[0], rfrag[0], _a, 0,0,0); \
    _a = __builtin_amdgcn_mfma_f32_16x16x32_bf16(src[1], rfrag[1], _a, 0,0,0); \
    _a = __builtin_amdgcn_mfma_f32_16x16x32_bf16(src[2], rfrag[2], _a, 0,0,0); \
    _a = __builtin_amdgcn_mfma_f32_16x16x32_bf16(src[3], rfrag[3], _a, 0,0,0); \
    const __half2 _h01 = __floats2half2_rn(__expf(_a[0]), __expf(_a[1]));      \
    const __half2 _h23 = __floats2half2_rn(__expf(_a[2]), __expf(_a[3]));      \
    const unsigned _byte = ((unsigned)(l15 * 512 + (t) * 32 + l4 * 8))         \
                           ^ (unsigned)(l15 << 4);                             \
    *(uint2*)(myls + _byte) =                                                  \
        make_uint2(*(const unsigned*)&_h01, *(const unsigned*)&_h23); }

__global__ __launch_bounds__(512, 4)
void write_wave_kernel(const s16x8* __restrict__ F,
                       const float* __restrict__ rinv,
                       float* __restrict__ out)
{
    __shared__ unsigned short lsw[8][4096];   // 8 waves x private 8KB

    const int tid  = threadIdx.x;
    const int lane = tid & 63;
    const int wv   = tid >> 6;          // 0..7
    const int l15  = lane & 15;
    const int l4   = lane >> 4;
    char* myls = (char*)&lsw[wv][0];

    // XCD swizzle (bijective on 1024)
    const int u    = ((blockIdx.x & 7) << 7) | (blockIdx.x >> 3);
    const int b    = u >> 8;
    const int tr   = u & 255;
    const s16x8* Fb = F + (size_t)b * FRAG_PER_B;

    s16x8 rfrag[4];
#pragma unroll
    for (int ks = 0; ks < 4; ++ks) rfrag[ks] = Fb[((size_t)tr * 4 + ks) * 64 + lane];

    const float* rvp = rinv + (size_t)b * SEQ + tr * 16;   // 16 row scales
    float* const obt = out + ((size_t)b * SEQ + tr * 16) * SEQ;

#pragma unroll
    for (int s = 0; s < 2; ++s) {
        const int strip = wv + s * 8;                      // 0..15 (256 cols)
        const s16x8* base = Fb + (size_t)(strip * 16) * 256 + lane;

        // compute 16 col-tiles into private stash, depth-3 prefetch
        s16x8 cA[4], cB[4], cC[4];
        LOADW(cA, 0)
        LOADW(cB, 1)
        LOADW(cC, 2)
#pragma unroll
        for (int i = 0; i < 6; ++i) {
            const int t = i * 3;
            { COMPW(cA, t)           if (t + 3 < 16) LOADW(cA, t + 3) }
            if (t + 1 < 16) { COMPW(cB, t + 1) if (t + 4 < 16) LOADW(cB, t + 4) }
            if (t + 2 < 16) { COMPW(cC, t + 2) if (t + 5 < 16) LOADW(cC, t + 5) }
        }

        // write phase (wave-private; only lgkmcnt ordering needed)
        float* obs = obt + strip * 256;
#pragma unroll
        for (int r = 0; r < 16; ++r) {
            const float rv = rvp[r];
            const unsigned byte = ((unsigned)(r * 512 + lane * 8)) ^ (unsigned)(r << 4);
            const uint2 d = *(const uint2*)(myls + byte);
            const float2 f01 = __half22float2(*(const __half2*)&d.x);
            const float2 f23 = __half22float2(*(const __half2*)&d.y);
            f32x4 pv;
            pv[0] = f01.x * rv;
            pv[1] = f01.y * rv;
            pv[2] = f23.x * rv;
            pv[3] = f23.y * rv;
            __builtin_nontemporal_store(pv, (f32x4*)(obs + (size_t)r * SEQ + lane * 4));
        }
    }
}

extern "C" void kernel_launch(void* const* d_in, const int* in_sizes, int n_in,
                              void* d_out, int out_size, void* d_ws, size_t ws_size,
                              hipStream_t stream)
{
    const float* query = (const float*)d_in[0];
    // d_in[1] = key (unused by the forward)
    const float* Wq    = (const float*)d_in[2];
    const float* bq    = (const float*)d_in[3];
    const float* wt    = (const float*)d_in[4];
    float* out = (float*)d_out;
    s16x8* F    = (s16x8*)d_ws;                                         // 4 MiB
    s16x8* WF   = (s16x8*)((char*)d_ws + (size_t)4 * 1024 * 1024);      // 256 KiB
    float* rinv = (float*)((char*)d_ws + (size_t)4 * 1024 * 1024 + 256 * 1024);  // 64 KiB

    wq_frag_kernel<<<dim3(256), dim3(64), 0, stream>>>(Wq, wt, WF);
    ctx_norm_kernel<<<dim3(ROWS_TOTAL / 32), dim3(512), 0, stream>>>(query, WF, bq, wt, F);
    rowsum_kernel<<<dim3(512), dim3(512), 0, stream>>>(F, rinv);
    write_wave_kernel<<<dim3(BATCH * TPB), dim3(512), 0, stream>>>(F, rinv, out);
}

// Round 17
// 107.409 us; speedup vs baseline: 1.0331x; 1.0331x over previous
//
#include <hip/hip_runtime.h>
#include <hip/hip_fp16.h>

// Problem constants
#define BATCH   4
#define SEQ     4096
#define DMODEL  1024
#define HDIM    120
#define ROWS_TOTAL (BATCH * SEQ)       // 16384
#define TPB     256                    // 16-row tiles per batch (SEQ/16)

typedef float f32x4 __attribute__((ext_vector_type(4)));
typedef short s16x8 __attribute__((ext_vector_type(8)));

// F layout (fragment-ordered ctx): s16x8 F[global_tile][ks][lane]
//   = ctx_n[tile*16 + (lane&15)][ks*32 + (lane>>4)*8 .. +8]  (bf16)
#define FRAG_PER_B ((size_t)TPB * 4 * 64)
// WF layout (fragment-ordered Wq*wt, bf16): s16x8 WF[(ct*32+ks)*64 + lane]

static __device__ __forceinline__ unsigned short f2bf(float f) {
    unsigned u = __float_as_uint(f);
    u += 0x7FFFu + ((u >> 16) & 1u);   // RNE
    return (unsigned short)(u >> 16);
}
static __device__ __forceinline__ s16x8 pack2x4(f32x4 lo, f32x4 hi) {
    s16x8 r;
#pragma unroll
    for (int i = 0; i < 4; ++i) r[i] = (short)f2bf(lo[i]);
#pragma unroll
    for (int i = 0; i < 4; ++i) r[4 + i] = (short)f2bf(hi[i]);
    return r;
}

// ---------------------------------------------------------------------------
// Kernel W (unchanged): Wq -> WF fragment-ordered bf16, wt folded in.
// ---------------------------------------------------------------------------
__global__ __launch_bounds__(64)
void wq_frag_kernel(const float* __restrict__ Wq, const float* __restrict__ wt,
                    s16x8* __restrict__ WF)
{
    const int lane = threadIdx.x;
    const int l15  = lane & 15;
    const int l4   = lane >> 4;
    const int ct   = blockIdx.x >> 5;
    const int ks   = blockIdx.x & 31;
    const int col  = ct * 16 + l15;

    f32x4 lo = (f32x4){0.f,0.f,0.f,0.f}, hi = lo;
    if (col < HDIM) {
        const float w = wt[col];
        const float* src = Wq + (size_t)col * DMODEL + ks * 32 + l4 * 8;
        lo = *(const f32x4*)(src);
        hi = *(const f32x4*)(src + 4);
#pragma unroll
        for (int i = 0; i < 4; ++i) { lo[i] *= w; hi[i] *= w; }
    }
    WF[((size_t)(ct * 32 + ks)) * 64 + lane] = pack2x4(lo, hi);
}

// ---------------------------------------------------------------------------
// Kernel A v3 (unchanged from R15): context GEMM + bias + L2-norm -> F.
// ---------------------------------------------------------------------------
__global__ __launch_bounds__(512)
void ctx_norm_kernel(const float* __restrict__ query,
                     const s16x8* __restrict__ WF,
                     const float* __restrict__ bq,
                     const float* __restrict__ wt,
                     s16x8* __restrict__ F)
{
    __shared__ unsigned short lA[2][32 * 72];
    __shared__ float lsq[32][4];
    __shared__ unsigned short lt[32][136];

    const int tid  = threadIdx.x;
    const int lane = tid & 63;
    const int wv   = tid >> 6;
    const int wr   = wv & 1;
    const int wc   = wv >> 1;
    const int l15  = lane & 15;
    const int l4   = lane >> 4;
    const int row0 = blockIdx.x * 32;

    const int arow = tid >> 4;
    const int achk = tid & 15;
    const float* aload = query + (size_t)(row0 + arow) * DMODEL + achk * 4;

    f32x4 acc[2];
#pragma unroll
    for (int n = 0; n < 2; ++n) acc[n] = (f32x4){0.f,0.f,0.f,0.f};

    auto stage = [&](int buf, const f32x4& v) {
        const unsigned u0 = (unsigned)f2bf(v[0]) | ((unsigned)f2bf(v[1]) << 16);
        const unsigned u1 = (unsigned)f2bf(v[2]) | ((unsigned)f2bf(v[3]) << 16);
        *(uint2*)&lA[buf][arow * 72 + achk * 4] = make_uint2(u0, u1);
    };

    f32x4 pr = *(const f32x4*)(aload);
    stage(0, pr);

    for (int slab = 0; slab < 16; ++slab) {
        __syncthreads();
        if (slab + 1 < 16) pr = *(const f32x4*)(aload + (slab + 1) * 64);
        const int buf = slab & 1;
#pragma unroll
        for (int ks2 = 0; ks2 < 2; ++ks2) {
            const int ks = slab * 2 + ks2;
            const s16x8 a = *(const s16x8*)&lA[buf][(wr * 16 + l15) * 72 + ks2 * 32 + l4 * 8];
#pragma unroll
            for (int n = 0; n < 2; ++n) {
                const s16x8 bfr = WF[((size_t)((wc * 2 + n) * 32 + ks)) * 64 + lane];
                acc[n] = __builtin_amdgcn_mfma_f32_16x16x32_bf16(a, bfr, acc[n], 0, 0, 0);
            }
        }
        if (slab + 1 < 16) stage(buf ^ 1, pr);
    }

    float sumsq[4] = {0.f,0.f,0.f,0.f};
#pragma unroll
    for (int n = 0; n < 2; ++n) {
        const int col = wc * 32 + n * 16 + l15;
        const float bqv = (col < HDIM) ? bq[col] * wt[col] : 0.f;
#pragma unroll
        for (int r = 0; r < 4; ++r) {
            const float v = acc[n][r] + bqv;
            acc[n][r] = v;
            sumsq[r] += v * v;
        }
    }
#pragma unroll
    for (int r = 0; r < 4; ++r) {
        float s = sumsq[r];
        s += __shfl_xor(s, 1);
        s += __shfl_xor(s, 2);
        s += __shfl_xor(s, 4);
        s += __shfl_xor(s, 8);
        sumsq[r] = s;
    }
    if (l15 == 0) {
#pragma unroll
        for (int r = 0; r < 4; ++r)
            lsq[wr * 16 + l4 * 4 + r][wc] = sumsq[r];
    }
    __syncthreads();
#pragma unroll
    for (int r = 0; r < 4; ++r) {
        const int lr = wr * 16 + l4 * 4 + r;
        const float s = lsq[lr][0] + lsq[lr][1] + lsq[lr][2] + lsq[lr][3];
        const float rinv = 1.f / fmaxf(sqrtf(s), 1e-12f);
#pragma unroll
        for (int n = 0; n < 2; ++n)
            lt[lr][wc * 32 + n * 16 + l15] = f2bf(acc[n][r] * rinv);
    }
    __syncthreads();
    {
        const int tl = wv >> 2;
        const int k4 = wv & 3;
        const s16x8 fr = *(const s16x8*)&lt[tl * 16 + l15][k4 * 32 + l4 * 8];
        F[((size_t)(blockIdx.x * 2 + tl) * 4 + k4) * 64 + lane] = fr;
    }
}

// ---------------------------------------------------------------------------
// Kernel B v7: PRODUCER-CONSUMER fused gram+softmax.
// 256 blocks x 1024 thr (16 waves) = exactly 1 block/CU, persistent.
// Block = 64 rows (4 tiles of 16) x 4096 cols. Unit = 16 rows x 512 cols
// (16KB f16 stash). Ring of 9 units (147KB LDS). 40 intervals:
//   producers (waves 0-7): interval k<32 computes unit k (tile k>>3,
//     cols (k&7)*512; wave strip 64 cols = 4 col-tiles, depth-2 prefetch),
//     exp -> f16 -> ring[k%9]; rowsum partials accumulate in registers
//     across the tile's 8 units, reduced to lsum at unit 7.
//   consumers (waves 8-15): interval k>=8 writes unit k-8 from ring[(k-8)%9]
//     (2 rows/wave x 512 cols = 4x 1KB full-line NT stores), scaling by
//     rinv from lsum (tile complete by lag-8 construction).
// Ring slot safety: compute slot k%9 != store slot (k-8)%9 (8 !≡ 0 mod 9);
// unit k+9 reuses slot k%9 one interval AFTER its store, across a barrier.
// ---------------------------------------------------------------------------
__global__ __launch_bounds__(1024)
void gram_pc_kernel(const s16x8* __restrict__ F, float* __restrict__ out)
{
    __shared__ unsigned short ring[9][16][512];   // 147456 B
    __shared__ float lsum[2][16][8];              // [tile&1][row][producer wave]

    const int tid  = threadIdx.x;
    const int lane = tid & 63;
    const int wv   = tid >> 6;          // 0..15
    const int l15  = lane & 15;
    const int l4   = lane >> 4;

    // XCD swizzle (bijective on 256): 32 contiguous 64-row groups per XCD
    const int u    = ((blockIdx.x & 7) << 5) | (blockIdx.x >> 3);
    const int b    = u >> 6;
    const int rgb  = u & 63;            // 64-row group within batch
    const s16x8* Fb = F + (size_t)b * FRAG_PER_B;

    // producer state
    s16x8 rfrag[4];
    float rs = 0.f;
    // consumer state
    const int sw = wv - 8;
    const int r0 = sw * 2, r1 = sw * 2 + 1;       // rows within tile (consumers)
    float rv0 = 0.f, rv1 = 0.f;

    auto loadC = [&](s16x8* cf, int gct) {
        const s16x8* p = Fb + (size_t)gct * 256 + lane;
#pragma unroll
        for (int ks = 0; ks < 4; ++ks) cf[ks] = p[ks * 64];
    };

    for (int k = 0; k < 40; ++k) {
        if (wv < 8) {
            // ---------------- producer ----------------
            if (k < 32) {
                const int t    = k >> 3;
                const int uc   = k & 7;
                const int slot = k % 9;
                if (uc == 0) {
#pragma unroll
                    for (int ks = 0; ks < 4; ++ks)
                        rfrag[ks] = Fb[((size_t)(rgb * 4 + t) * 4 + ks) * 64 + lane];
                    rs = 0.f;
                }
                char* sb = (char*)&ring[slot][0][0];
                const int gct0 = uc * 32 + wv * 4;          // global col-tile base
                const unsigned swz = (unsigned)((l15 & 7) << 4);

                auto comp = [&](const s16x8* cf, int i) {
                    f32x4 a = (f32x4){0.f,0.f,0.f,0.f};
#pragma unroll
                    for (int ks = 0; ks < 4; ++ks)
                        a = __builtin_amdgcn_mfma_f32_16x16x32_bf16(cf[ks], rfrag[ks], a, 0, 0, 0);
                    const float e0 = __expf(a[0]), e1 = __expf(a[1]);
                    const float e2 = __expf(a[2]), e3 = __expf(a[3]);
                    rs += (e0 + e1) + (e2 + e3);
                    const __half2 h01 = __floats2half2_rn(e0, e1);
                    const __half2 h23 = __floats2half2_rn(e2, e3);
                    // lane: row l15, local cols wv*64 + i*16 + l4*4 .. +4
                    const unsigned byte = ((unsigned)(l15 * 1024 + wv * 128 + i * 32 + l4 * 8)) ^ swz;
                    *(uint2*)(sb + byte) = make_uint2(*(const unsigned*)&h01, *(const unsigned*)&h23);
                };

                s16x8 cf0[4], cf1[4];
                loadC(cf0, gct0);
                loadC(cf1, gct0 + 1);
                comp(cf0, 0); loadC(cf0, gct0 + 2);
                comp(cf1, 1); loadC(cf1, gct0 + 3);
                comp(cf0, 2);
                comp(cf1, 3);

                if (uc == 7) {      // tile complete: reduce & publish rowsums
                    float tsum = rs;
                    tsum += __shfl_xor(tsum, 16);
                    tsum += __shfl_xor(tsum, 32);
                    if (lane < 16) lsum[t & 1][l15][wv] = tsum;
                }
            }
        } else {
            // ---------------- consumer ----------------
            if (k >= 8) {
                const int km   = k - 8;
                const int ts   = km >> 3;
                const int uc   = km & 7;
                const int slot = km % 9;
                if (uc == 0) {      // tile ts rowsums published last interval
                    float s0 = 0.f, s1 = 0.f;
#pragma unroll
                    for (int w = 0; w < 8; ++w) {
                        s0 += lsum[ts & 1][r0][w];
                        s1 += lsum[ts & 1][r1][w];
                    }
                    rv0 = 1.f / s0;
                    rv1 = 1.f / s1;
                }
                const char* sb = (const char*)&ring[slot][0][0];
                float* ob0 = out + ((size_t)b * SEQ + rgb * 64 + ts * 16 + r0) * SEQ + uc * 512;
                float* ob1 = out + ((size_t)b * SEQ + rgb * 64 + ts * 16 + r1) * SEQ + uc * 512;
#pragma unroll
                for (int i = 0; i < 2; ++i) {
                    const unsigned byA = ((unsigned)(r0 * 1024 + i * 512 + lane * 8))
                                         ^ ((unsigned)((r0 & 7) << 4));
                    const uint2 dA = *(const uint2*)(sb + byA);
                    const float2 a01 = __half22float2(*(const __half2*)&dA.x);
                    const float2 a23 = __half22float2(*(const __half2*)&dA.y);
                    f32x4 pA;
                    pA[0] = a01.x * rv0; pA[1] = a01.y * rv0;
                    pA[2] = a23.x * rv0; pA[3] = a23.y * rv0;
                    __builtin_nontemporal_store(pA, (f32x4*)(ob0 + i * 256 + lane * 4));

                    const unsigned byB = ((unsigned)(r1 * 1024 + i * 512 + lane * 8))
                                         ^ ((unsigned)((r1 & 7) << 4));
                    const uint2 dB = *(const uint2*)(sb + byB);
                    const float2 b01 = __half22float2(*(const __half2*)&dB.x);
                    const float2 b23 = __half22float2(*(const __half2*)&dB.y);
                    f32x4 pB;
                    pB[0] = b01.x * rv1; pB[1] = b01.y * rv1;
                    pB[2] = b23.x * rv1; pB[3] = b23.y * rv1;
                    __builtin_nontemporal_store(pB, (f32x4*)(ob1 + i * 256 + lane * 4));
                }
            }
        }
        __syncthreads();
    }
}

extern "C" void kernel_launch(void* const* d_in, const int* in_sizes, int n_in,
                              void* d_out, int out_size, void* d_ws, size_t ws_size,
                              hipStream_t stream)
{
    const float* query = (const float*)d_in[0];
    // d_in[1] = key (unused by the forward)
    const float* Wq    = (const float*)d_in[2];
    const float* bq    = (const float*)d_in[3];
    const float* wt    = (const float*)d_in[4];
    float* out = (float*)d_out;
    s16x8* F  = (s16x8*)d_ws;                               // 4 MiB
    s16x8* WF = (s16x8*)((char*)d_ws + (size_t)4 * 1024 * 1024);  // 256 KiB

    wq_frag_kernel<<<dim3(256), dim3(64), 0, stream>>>(Wq, wt, WF);
    ctx_norm_kernel<<<dim3(ROWS_TOTAL / 32), dim3(512), 0, stream>>>(query, WF, bq, wt, F);
    gram_pc_kernel<<<dim3(256), dim3(1024), 0, stream>>>(F, out);
}